// Round 12
// baseline (412.192 us; speedup 1.0000x reference)
//
#include <hip/hip_runtime.h>

#define SEQ   512
#define BATCH 256
#define DIN   128
#define HID   256
#define NOISE 0.99f

__device__ __forceinline__ float dot4(float4 a, float4 b) {
    return fmaf(a.x, b.x, fmaf(a.y, b.y, fmaf(a.z, b.z, a.w * b.w)));
}
// round-11 validated activations (v_rcp; error bucket unchanged vs exact div)
__device__ __forceinline__ float sigmoid_(float x) {
    return __builtin_amdgcn_rcpf(1.0f + __expf(-x));
}
__device__ __forceinline__ float tanh_(float x) {
    float ax = fabsf(x);
    float e  = __expf(2.0f * ax);
    float t  = __builtin_amdgcn_rcpf(e + 1.0f);
    float r  = 1.0f - 2.0f * t;
    return copysignf(r, x);
}
template <int CTRL>
__device__ __forceinline__ float dppmov(float v) {
    return __int_as_float(__builtin_amdgcn_mov_dpp(__float_as_int(v), CTRL, 0xF, 0xF, false));
}
__device__ __forceinline__ float swap16_sum(float v) {
    float a = v, b;
    asm("v_mov_b32 %1, %0\n\tv_permlane16_swap_b32 %0, %1" : "+v"(a), "=&v"(b));
    return a + b;
}
__device__ __forceinline__ float swap32_sum(float v) {
    float a = v, b;
    asm("v_mov_b32 %1, %0\n\tv_permlane32_swap_b32 %0, %1" : "+v"(a), "=&v"(b));
    return a + b;
}
// LDS-only barrier (no vmcnt drain) — round-10 validated
__device__ __forceinline__ void barrier_lds() {
    asm volatile("s_waitcnt lgkmcnt(0)\n\ts_barrier" ::: "memory");
}

// ---------------------------------------------------------------------------
// Kernel 1: pre[s,b,p] (unchanged, validated rounds 2..11)
// ---------------------------------------------------------------------------
__global__ __launch_bounds__(256, 4) void pre_gemm(
    const float* __restrict__ x,
    const float* __restrict__ w_lin,
    const float* __restrict__ b_lin,
    const float* __restrict__ theta,
    float* pre, int pstride)
{
    __shared__ float wlds[16 * 132];
    const int t = threadIdx.x;
    for (int i = t; i < 16 * 128; i += 256) {
        int pp = i >> 7, dd = i & 127;
        wlds[pp * 132 + dd] = w_lin[pp * 384 + dd];
    }
    __syncthreads();
    const int s = blockIdx.x >> 4;
    const int b = ((blockIdx.x & 15) << 4) + (t >> 4);
    const int p = t & 15;
    const float* xr = x + ((size_t)s * BATCH + b) * DIN;
    const float* wr = &wlds[p * 132];
    float acc = b_lin[p] + theta[p];
    #pragma unroll 8
    for (int d = 0; d < 32; ++d)
        acc += dot4(*(const float4*)(xr + d * 4), *(const float4*)(wr + d * 4));
    pre[((size_t)s * BATCH + b) * pstride + p] = acc;
}

// ---------------------------------------------------------------------------
// Kernel 2: persistent recurrence — round-11 arithmetic (bitwise), TWO chains
// per block software-pipelined half a step apart:
//   interval X_k: P2(A,k) || P1(B,k)   ; barrier
//   interval Y_k: P1(A,k+1) || P2(B,k) ; barrier
// Each chain's stalls (LDS latency, trans chains, weight reloads, barrier)
// are filled by the other chain's independent phase in the same wave.
// ---------------------------------------------------------------------------
__global__ __launch_bounds__(256, 1) void qlstm_rec(
    const float* __restrict__ w_lin,
    const float* __restrict__ w_map,
    const float* __restrict__ b_map,
    const float* pre, int pstride,    // may alias out (no restrict!)
    float* out)
{
    const int bA = blockIdx.x * 2;
    const int bB = bA + 1;
    const int t = threadIdx.x;
    const int l = t & 63;
    const int g = t >> 6;        // wave == gate
    const int q = l & 3;
    const int j = l >> 2;
    const int p = (g << 2) | q;

    __shared__ __align__(16) float hxA_lds[HID];
    __shared__ __align__(16) float hxB_lds[HID];
    __shared__ __align__(16) float actsA_lds[16];
    __shared__ __align__(16) float actsB_lds[16];

    // phase-1 weights (shared by both chains), swizzle folded into init
    const int sig = (j >> 1) & 3;
    const float* wp = w_lin + p * 384 + 128 + j * 16;
    const float4 wh0 = *(const float4*)(wp + ((0 ^ sig) << 2));
    const float4 wh1 = *(const float4*)(wp + ((1 ^ sig) << 2));
    const float4 wh2 = *(const float4*)(wp + ((2 ^ sig) << 2));
    const float4 wh3 = *(const float4*)(wp + ((3 ^ sig) << 2));

    // phase-2 weights: thread t owns h = t (shared by both chains)
    const float4 wm0 = ((const float4*)w_map)[0 * 256 + t];
    const float4 wm1 = ((const float4*)w_map)[1 * 256 + t];
    const float4 wm2 = ((const float4*)w_map)[2 * 256 + t];
    const float4 wm3 = ((const float4*)w_map)[3 * 256 + t];
    const float bm0 = b_map[t];
    const float bm1 = b_map[256 + t];
    const float bm2 = b_map[512 + t];
    const float bm3 = b_map[768 + t];

    // swizzled hx read offsets (per chain buffer)
    const int o0 = j * 16 + ((0 ^ sig) << 2);
    const int o1 = j * 16 + ((1 ^ sig) << 2);
    const int o2 = j * 16 + ((2 ^ sig) << 2);
    const int o3 = j * 16 + ((3 ^ sig) << 2);

    // per-chain pre pipelines (2 steps ahead)
    const size_t sstride = (size_t)BATCH * pstride;
    const float* pbA = pre + (size_t)bA * pstride + p;
    const float* pbB = pre + (size_t)bB * pstride + p;
    float pxB0 = pbB[0];
    float pxB1 = pbB[sstride];

    hxA_lds[t] = 0.0f;
    hxB_lds[t] = 0.0f;
    float hxA = 0.0f, cxA = 0.0f, hxB = 0.0f, cxB = 0.0f;
    float* out_hx = out + (size_t)SEQ * BATCH * HID;
    float* out_cx = out_hx + BATCH * HID;

    // P1 body: reads hx fragment regs, returns act (all lanes; lanes<4 valid)
    auto P1 = [&](float4 ha0, float4 ha1, float4 ha2, float4 ha3, float pxu) -> float {
        float acc = dot4(wh0, ha0) + dot4(wh1, ha1)
                  + dot4(wh2, ha2) + dot4(wh3, ha3);
        acc += dppmov<0x124>(acc);
        acc += dppmov<0x128>(acc);
        acc  = swap16_sum(acc);
        acc  = swap32_sum(acc);
        const float A  = __cosf(acc + pxu);
        const float Bv = dppmov<0xB1>(A);
        const float Cv = dppmov<0x4E>(A);
        const float Dv = dppmov<0x4E>(Bv);
        const float t1 = Cv * Dv;
        const float u  = (q & 1) ? (A * Bv) : ((q == 2) ? A : Bv);
        const float v  = (q == 1) ? 1.0f : t1;
        const float ez = NOISE * u * v;
        return (g == 2) ? tanh_(ez) : sigmoid_(ez);
    };
    // P2 body: acts fragments -> updates cx,hx
    auto P2 = [&](float4 a0, float4 a1, float4 a2, float4 a3, float& cx, float& hx) {
        const float fv = bm0 + dot4(wm0, a0);
        const float iv = bm1 + dot4(wm1, a1);
        const float gv = bm2 + dot4(wm2, a2);
        const float ov = bm3 + dot4(wm3, a3);
        cx = fmaf(fv, cx, iv * gv);
        hx = ov * tanh_(cx);
    };

    barrier_lds();

    // ---- prologue: P1(A,0) ------------------------------------------------
    {
        const float4 ha0 = *(const float4*)(hxA_lds + o0);
        const float4 ha1 = *(const float4*)(hxA_lds + o1);
        const float4 ha2 = *(const float4*)(hxA_lds + o2);
        const float4 ha3 = *(const float4*)(hxA_lds + o3);
        const float act = P1(ha0, ha1, ha2, ha3, pbA[0]);
        if (l < 4) actsA_lds[(g << 2) | l] = act;
    }
    float pxA0 = pbA[sstride];          // pre for A step 1
    float pxA1 = pbA[2 * sstride];      // pre for A step 2
    barrier_lds();

    for (int k = 0; k < SEQ; ++k) {
        // ================= interval X: P2(A,k) || P1(B,k) ==================
        {
            const float4 aA0 = *(const float4*)&actsA_lds[0];
            const float4 aA1 = *(const float4*)&actsA_lds[4];
            const float4 aA2 = *(const float4*)&actsA_lds[8];
            const float4 aA3 = *(const float4*)&actsA_lds[12];
            const float4 hB0 = *(const float4*)(hxB_lds + o0);
            const float4 hB1 = *(const float4*)(hxB_lds + o1);
            const float4 hB2 = *(const float4*)(hxB_lds + o2);
            const float4 hB3 = *(const float4*)(hxB_lds + o3);

            P2(aA0, aA1, aA2, aA3, cxA, hxA);

            const float pxuB = pxB0;
            pxB0 = pxB1;
            const int sB2 = (k + 2 < SEQ) ? k + 2 : SEQ - 1;
            pxB1 = pbB[(size_t)sB2 * sstride];
            const float actB = P1(hB0, hB1, hB2, hB3, pxuB);

            hxA_lds[t] = hxA;
            out[((size_t)k * BATCH + bA) * HID + t] = hxA;
            if (l < 4) actsB_lds[(g << 2) | l] = actB;
        }
        barrier_lds();

        // ================= interval Y: P1(A,k+1) || P2(B,k) ================
        {
            const float4 hA0 = *(const float4*)(hxA_lds + o0);
            const float4 hA1 = *(const float4*)(hxA_lds + o1);
            const float4 hA2 = *(const float4*)(hxA_lds + o2);
            const float4 hA3 = *(const float4*)(hxA_lds + o3);
            const float4 aB0 = *(const float4*)&actsB_lds[0];
            const float4 aB1 = *(const float4*)&actsB_lds[4];
            const float4 aB2 = *(const float4*)&actsB_lds[8];
            const float4 aB3 = *(const float4*)&actsB_lds[12];

            P2(aB0, aB1, aB2, aB3, cxB, hxB);

            const float pxuA = pxA0;
            pxA0 = pxA1;
            const int sA2 = (k + 3 < SEQ) ? k + 3 : SEQ - 1;
            pxA1 = pbA[(size_t)sA2 * sstride];
            const float actA = P1(hA0, hA1, hA2, hA3, pxuA);  // step k+1 (k=511: dummy)

            hxB_lds[t] = hxB;
            out[((size_t)k * BATCH + bB) * HID + t] = hxB;
            if (l < 4) actsA_lds[(g << 2) | l] = actA;
        }
        barrier_lds();
    }

    out_hx[(size_t)bA * HID + t] = hxA;
    out_cx[(size_t)bA * HID + t] = cxA;
    out_hx[(size_t)bB * HID + t] = hxB;
    out_cx[(size_t)bB * HID + t] = cxB;
}

extern "C" void kernel_launch(void* const* d_in, const int* in_sizes, int n_in,
                              void* d_out, int out_size, void* d_ws, size_t ws_size,
                              hipStream_t stream) {
    const float* x     = (const float*)d_in[0];
    const float* w_lin = (const float*)d_in[1];
    const float* b_lin = (const float*)d_in[2];
    const float* w_map = (const float*)d_in[3];
    const float* b_map = (const float*)d_in[4];
    const float* theta = (const float*)d_in[5];
    float* out = (float*)d_out;

    const size_t pre_bytes = (size_t)SEQ * BATCH * 16 * sizeof(float);
    float* pre;
    int pstride;
    if (ws_size >= pre_bytes) {
        pre = (float*)d_ws;
        pstride = 16;
    } else {
        pre = out;                        // reads run >=2 rows ahead of writes
        pstride = HID;
    }

    pre_gemm<<<dim3(SEQ * 16), dim3(256), 0, stream>>>(x, w_lin, b_lin, theta, pre, pstride);
    qlstm_rec<<<dim3(BATCH / 2), dim3(256), 0, stream>>>(w_lin, w_map, b_map, pre, pstride, out);
}

// Round 13
// 311.248 us; speedup vs baseline: 1.3243x; 1.3243x over previous
//
#include <hip/hip_runtime.h>

#define SEQ   512
#define BATCH 256
#define DIN   128
#define HID   256
#define NOISE 0.99f

__device__ __forceinline__ float dot4(float4 a, float4 b) {
    return fmaf(a.x, b.x, fmaf(a.y, b.y, fmaf(a.z, b.z, a.w * b.w)));
}
// round-11 validated activations (v_rcp; error bucket unchanged vs exact div)
__device__ __forceinline__ float sigmoid_(float x) {
    return __builtin_amdgcn_rcpf(1.0f + __expf(-x));
}
__device__ __forceinline__ float tanh_(float x) {
    float ax = fabsf(x);
    float e  = __expf(2.0f * ax);
    float t  = __builtin_amdgcn_rcpf(e + 1.0f);
    float r  = 1.0f - 2.0f * t;
    return copysignf(r, x);
}
template <int CTRL>
__device__ __forceinline__ float dppmov(float v) {
    return __int_as_float(__builtin_amdgcn_mov_dpp(__float_as_int(v), CTRL, 0xF, 0xF, false));
}
__device__ __forceinline__ float swap16_sum(float v) {
    float a = v, b;
    asm("v_mov_b32 %1, %0\n\tv_permlane16_swap_b32 %0, %1" : "+v"(a), "=&v"(b));
    return a + b;
}
__device__ __forceinline__ float swap32_sum(float v) {
    float a = v, b;
    asm("v_mov_b32 %1, %0\n\tv_permlane32_swap_b32 %0, %1" : "+v"(a), "=&v"(b));
    return a + b;
}
// LDS-only barrier (no vmcnt drain) — round-10 validated
__device__ __forceinline__ void barrier_lds() {
    asm volatile("s_waitcnt lgkmcnt(0)\n\ts_barrier" ::: "memory");
}

// ---------------------------------------------------------------------------
// Kernel 1: pre[s,b,p] (unchanged, validated rounds 2..12)
// ---------------------------------------------------------------------------
__global__ __launch_bounds__(256, 4) void pre_gemm(
    const float* __restrict__ x,
    const float* __restrict__ w_lin,
    const float* __restrict__ b_lin,
    const float* __restrict__ theta,
    float* pre, int pstride)
{
    __shared__ float wlds[16 * 132];
    const int t = threadIdx.x;
    for (int i = t; i < 16 * 128; i += 256) {
        int pp = i >> 7, dd = i & 127;
        wlds[pp * 132 + dd] = w_lin[pp * 384 + dd];
    }
    __syncthreads();
    const int s = blockIdx.x >> 4;
    const int b = ((blockIdx.x & 15) << 4) + (t >> 4);
    const int p = t & 15;
    const float* xr = x + ((size_t)s * BATCH + b) * DIN;
    const float* wr = &wlds[p * 132];
    float acc = b_lin[p] + theta[p];
    #pragma unroll 8
    for (int d = 0; d < 32; ++d)
        acc += dot4(*(const float4*)(xr + d * 4), *(const float4*)(wr + d * 4));
    pre[((size_t)s * BATCH + b) * pstride + p] = acc;
}

// ---------------------------------------------------------------------------
// Kernel 2: persistent recurrence — round-11 program VERBATIM per chain, but
// TWO chains per block as two independent 4-wave groups (512 threads).
// Chain c = waves 4c..4c+3 runs batch 2*blockIdx+c with its own LDS buffers.
// Every SIMD hosts one wave of each chain: chain A's LDS/transcendental/
// reload stalls are filled by chain B's issue (pure TLP — no arithmetic or
// per-wave program change, bitwise round-11 output).
// ---------------------------------------------------------------------------
__global__ __launch_bounds__(512, 1) void qlstm_rec(
    const float* __restrict__ w_lin,
    const float* __restrict__ w_map,
    const float* __restrict__ b_map,
    const float* pre, int pstride,    // may alias out (no restrict!)
    float* out)
{
    const int t  = threadIdx.x;
    const int c  = t >> 8;           // chain 0/1 (waves 0-3 vs 4-7)
    const int tt = t & 255;          // round-11 thread id within the chain
    const int b  = blockIdx.x * 2 + c;
    const int l  = tt & 63;
    const int g  = tt >> 6;          // wave-within-group == gate
    const int q  = l & 3;
    const int j  = l >> 2;
    const int p  = (g << 2) | q;

    __shared__ __align__(16) float hx_lds[2][HID];
    __shared__ __align__(16) float acts_lds[2][16];

    // hx-part weights; swizzle folded into init (round 2/11)
    const int sig = (j >> 1) & 3;
    const float* wp = w_lin + p * 384 + 128 + j * 16;
    const float4 wh0 = *(const float4*)(wp + ((0 ^ sig) << 2));
    const float4 wh1 = *(const float4*)(wp + ((1 ^ sig) << 2));
    const float4 wh2 = *(const float4*)(wp + ((2 ^ sig) << 2));
    const float4 wh3 = *(const float4*)(wp + ((3 ^ sig) << 2));

    // phase-2 weights: thread tt owns h = tt
    const float4 wm0 = ((const float4*)w_map)[0 * 256 + tt];
    const float4 wm1 = ((const float4*)w_map)[1 * 256 + tt];
    const float4 wm2 = ((const float4*)w_map)[2 * 256 + tt];
    const float4 wm3 = ((const float4*)w_map)[3 * 256 + tt];
    const float bm0 = b_map[tt];
    const float bm1 = b_map[256 + tt];
    const float bm2 = b_map[512 + tt];
    const float bm3 = b_map[768 + tt];

    // bank-conflict-free hx read addresses (XOR swizzle on the read side)
    const float* hr = &hx_lds[c][j * 16];
    const float* hr0 = hr + ((0 ^ sig) << 2);
    const float* hr1 = hr + ((1 ^ sig) << 2);
    const float* hr2 = hr + ((2 ^ sig) << 2);
    const float* hr3 = hr + ((3 ^ sig) << 2);

    // pre prefetch: 2 steps ahead (safe vs. the out-row overwrite when aliased)
    const float*  pb      = pre + (size_t)b * pstride + p;
    const size_t  sstride = (size_t)BATCH * pstride;
    float px0 = pb[0];
    float px1 = pb[sstride];

    hx_lds[c][tt] = 0.0f;
    float hx = 0.0f, cx = 0.0f;
    float* out_seq = out;
    float* out_hx  = out + (size_t)SEQ * BATCH * HID;
    float* out_cx  = out_hx + BATCH * HID;
    barrier_lds();

    for (int s = 0; s < SEQ; ++s) {
        const float pxu = px0;
        px0 = px1;
        const int s2 = (s + 2 < SEQ) ? s + 2 : SEQ - 1;
        px1 = pb[(size_t)s2 * sstride];

        // ---- phase 1: hx matvec + reduce (VALU comms) + quantum + act ------
        const float4 ha0 = *(const float4*)hr0;
        const float4 ha1 = *(const float4*)hr1;
        const float4 ha2 = *(const float4*)hr2;
        const float4 ha3 = *(const float4*)hr3;
        float acc = dot4(wh0, ha0) + dot4(wh1, ha1)
                  + dot4(wh2, ha2) + dot4(wh3, ha3);
        acc += dppmov<0x124>(acc);   // += lane+4  (row_ror:4)
        acc += dppmov<0x128>(acc);   // += lane+8  (row_ror:8)
        acc  = swap16_sum(acc);      // += lane^16
        acc  = swap32_sum(acc);      // += lane^32

        const float A  = __cosf(acc + pxu);      // pre includes b_lin + theta
        const float Bv = dppmov<0xB1>(A);        // quad_perm xor1 -> C_{q^1}
        const float Cv = dppmov<0x4E>(A);        // quad_perm xor2 -> C_{q^2}
        const float Dv = dppmov<0x4E>(Bv);       //                -> C_{q^3}

        const float t1 = Cv * Dv;
        const float u  = (q & 1) ? (A * Bv) : ((q == 2) ? A : Bv);
        const float v  = (q == 1) ? 1.0f : t1;
        const float ez = NOISE * u * v;
        const float act = (g == 2) ? tanh_(ez) : sigmoid_(ez);
        if (l < 4) acts_lds[c][(g << 2) | l] = act;
        barrier_lds();                            // B1: acts visible (LDS only)

        // ---- phase 2: gate matvec + cell update ---------------------------
        const float4 a0 = *(const float4*)&acts_lds[c][0];
        const float4 a1 = *(const float4*)&acts_lds[c][4];
        const float4 a2 = *(const float4*)&acts_lds[c][8];
        const float4 a3 = *(const float4*)&acts_lds[c][12];

        const float fv = bm0 + dot4(wm0, a0);
        const float iv = bm1 + dot4(wm1, a1);
        const float gv = bm2 + dot4(wm2, a2);
        const float ov = bm3 + dot4(wm3, a3);

        cx = fmaf(fv, cx, iv * gv);
        hx = ov * tanh_(cx);

        hx_lds[c][tt] = hx;
        out_seq[((size_t)s * BATCH + b) * HID + tt] = hx;
        barrier_lds();                            // B2: hx visible (LDS only)
    }

    out_hx[(size_t)b * HID + tt] = hx;
    out_cx[(size_t)b * HID + tt] = cx;
}

extern "C" void kernel_launch(void* const* d_in, const int* in_sizes, int n_in,
                              void* d_out, int out_size, void* d_ws, size_t ws_size,
                              hipStream_t stream) {
    const float* x     = (const float*)d_in[0];
    const float* w_lin = (const float*)d_in[1];
    const float* b_lin = (const float*)d_in[2];
    const float* w_map = (const float*)d_in[3];
    const float* b_map = (const float*)d_in[4];
    const float* theta = (const float*)d_in[5];
    float* out = (float*)d_out;

    const size_t pre_bytes = (size_t)SEQ * BATCH * 16 * sizeof(float);
    float* pre;
    int pstride;
    if (ws_size >= pre_bytes) {
        pre = (float*)d_ws;
        pstride = 16;
    } else {
        pre = out;                        // reads run >=2 rows ahead of writes
        pstride = HID;
    }

    pre_gemm<<<dim3(SEQ * 16), dim3(256), 0, stream>>>(x, w_lin, b_lin, theta, pre, pstride);
    qlstm_rec<<<dim3(BATCH / 2), dim3(512), 0, stream>>>(w_lin, w_map, b_map, pre, pstride, out);
}

// Round 14
// 286.205 us; speedup vs baseline: 1.4402x; 1.0875x over previous
//
#include <hip/hip_runtime.h>

#define SEQ   512
#define BATCH 256
#define DIN   128
#define HID   256
#define NOISE 0.99f

__device__ __forceinline__ float dot4(float4 a, float4 b) {
    return fmaf(a.x, b.x, fmaf(a.y, b.y, fmaf(a.z, b.z, a.w * b.w)));
}
// round-11 validated activations (v_rcp; error bucket unchanged vs exact div)
__device__ __forceinline__ float sigmoid_(float x) {
    return __builtin_amdgcn_rcpf(1.0f + __expf(-x));
}
__device__ __forceinline__ float tanh_(float x) {
    float ax = fabsf(x);
    float e  = __expf(2.0f * ax);
    float t  = __builtin_amdgcn_rcpf(e + 1.0f);
    float r  = 1.0f - 2.0f * t;
    return copysignf(r, x);
}
template <int CTRL>
__device__ __forceinline__ float dppmov(float v) {
    return __int_as_float(__builtin_amdgcn_mov_dpp(__float_as_int(v), CTRL, 0xF, 0xF, false));
}
__device__ __forceinline__ float swap16_sum(float v) {
    float a = v, b;
    asm("v_mov_b32 %1, %0\n\tv_permlane16_swap_b32 %0, %1" : "+v"(a), "=&v"(b));
    return a + b;
}
__device__ __forceinline__ float swap32_sum(float v) {
    float a = v, b;
    asm("v_mov_b32 %1, %0\n\tv_permlane32_swap_b32 %0, %1" : "+v"(a), "=&v"(b));
    return a + b;
}
__device__ __forceinline__ float rdlanef(float v, int lane) {
    return __int_as_float(__builtin_amdgcn_readlane(__float_as_int(v), lane));
}
// LDS-only barrier (no vmcnt drain) — round-10 validated
__device__ __forceinline__ void barrier_lds() {
    asm volatile("s_waitcnt lgkmcnt(0)\n\ts_barrier" ::: "memory");
}

// ---------------------------------------------------------------------------
// Kernel 1: pre[s,b,p] (unchanged, validated rounds 2..13)
// ---------------------------------------------------------------------------
__global__ __launch_bounds__(256, 4) void pre_gemm(
    const float* __restrict__ x,
    const float* __restrict__ w_lin,
    const float* __restrict__ b_lin,
    const float* __restrict__ theta,
    float* pre, int pstride)
{
    __shared__ float wlds[16 * 132];
    const int t = threadIdx.x;
    for (int i = t; i < 16 * 128; i += 256) {
        int pp = i >> 7, dd = i & 127;
        wlds[pp * 132 + dd] = w_lin[pp * 384 + dd];
    }
    __syncthreads();
    const int s = blockIdx.x >> 4;
    const int b = ((blockIdx.x & 15) << 4) + (t >> 4);
    const int p = t & 15;
    const float* xr = x + ((size_t)s * BATCH + b) * DIN;
    const float* wr = &wlds[p * 132];
    float acc = b_lin[p] + theta[p];
    #pragma unroll 8
    for (int d = 0; d < 32; ++d)
        acc += dot4(*(const float4*)(xr + d * 4), *(const float4*)(wr + d * 4));
    pre[((size_t)s * BATCH + b) * pstride + p] = acc;
}

// ---------------------------------------------------------------------------
// Kernel 2: persistent recurrence — round-11 arithmetic (bitwise) with the
// acts LDS round-trip replaced by an in-wave readlane broadcast:
//   gates[g] depends ONLY on acts[g] (einsum 'ghq,gbq->gbh'), and wave g owns
//   acts[g] at lanes 0..3. So wave g broadcasts its 4 acts to SGPRs and
//   computes gate_g[h] for h=4l..4l+3 (same dot4 chains, same values),
//   writes one b128; phase B reads 4 b32 gate values and updates the cell.
// Chain: hx-read + P1 + readlane + matvec + B1 + gates-read + update + B2.
// ---------------------------------------------------------------------------
__global__ __launch_bounds__(256, 1) void qlstm_rec(
    const float* __restrict__ w_lin,
    const float* __restrict__ w_map,
    const float* __restrict__ b_map,
    const float* pre, int pstride,    // may alias out (no restrict!)
    float* out)
{
    const int b = blockIdx.x;
    const int t = threadIdx.x;
    const int l = t & 63;
    const int g = t >> 6;        // wave index == gate
    const int q = l & 3;
    const int j = l >> 2;        // 0..15
    const int p = (g << 2) | q;

    __shared__ __align__(16) float hx_lds[HID];
    __shared__ __align__(16) float gates_lds[4][HID];

    // hx-part weights; swizzle folded into init (round 2/11)
    const int sig = (j >> 1) & 3;
    const float* wp = w_lin + p * 384 + 128 + j * 16;
    const float4 wh0 = *(const float4*)(wp + ((0 ^ sig) << 2));
    const float4 wh1 = *(const float4*)(wp + ((1 ^ sig) << 2));
    const float4 wh2 = *(const float4*)(wp + ((2 ^ sig) << 2));
    const float4 wh3 = *(const float4*)(wp + ((3 ^ sig) << 2));

    // gate-matvec weights: wave g, lane l owns h = 4l..4l+3 of gate g
    const float4 wmg0 = ((const float4*)w_map)[g * 256 + 4 * l + 0];
    const float4 wmg1 = ((const float4*)w_map)[g * 256 + 4 * l + 1];
    const float4 wmg2 = ((const float4*)w_map)[g * 256 + 4 * l + 2];
    const float4 wmg3 = ((const float4*)w_map)[g * 256 + 4 * l + 3];
    const float4 bmg  = *(const float4*)(b_map + g * 256 + 4 * l);

    // bank-conflict-free hx read addresses (XOR swizzle on the read side)
    const float* hr = &hx_lds[j * 16];
    const float* hr0 = hr + ((0 ^ sig) << 2);
    const float* hr1 = hr + ((1 ^ sig) << 2);
    const float* hr2 = hr + ((2 ^ sig) << 2);
    const float* hr3 = hr + ((3 ^ sig) << 2);

    // pre prefetch: 2 steps ahead (safe vs. the out-row overwrite when aliased)
    const float*  pb      = pre + (size_t)b * pstride + p;
    const size_t  sstride = (size_t)BATCH * pstride;
    float px0 = pb[0];
    float px1 = pb[sstride];

    hx_lds[t] = 0.0f;
    float hx = 0.0f, cx = 0.0f;
    float* out_seq = out;
    float* out_hx  = out + (size_t)SEQ * BATCH * HID;
    float* out_cx  = out_hx + BATCH * HID;
    barrier_lds();

    for (int s = 0; s < SEQ; ++s) {
        const float pxu = px0;
        px0 = px1;
        const int s2 = (s + 2 < SEQ) ? s + 2 : SEQ - 1;
        px1 = pb[(size_t)s2 * sstride];

        // ---- phase A: hx matvec + reduce + quantum + act (round-11 bitwise)
        const float4 ha0 = *(const float4*)hr0;
        const float4 ha1 = *(const float4*)hr1;
        const float4 ha2 = *(const float4*)hr2;
        const float4 ha3 = *(const float4*)hr3;
        float acc = dot4(wh0, ha0) + dot4(wh1, ha1)
                  + dot4(wh2, ha2) + dot4(wh3, ha3);
        acc += dppmov<0x124>(acc);   // += lane+4  (row_ror:4)
        acc += dppmov<0x128>(acc);   // += lane+8  (row_ror:8)
        acc  = swap16_sum(acc);      // += lane^16
        acc  = swap32_sum(acc);      // += lane^32

        const float A  = __cosf(acc + pxu);      // pre includes b_lin + theta
        const float Bv = dppmov<0xB1>(A);        // quad_perm xor1 -> C_{q^1}
        const float Cv = dppmov<0x4E>(A);        // quad_perm xor2 -> C_{q^2}
        const float Dv = dppmov<0x4E>(Bv);       //                -> C_{q^3}

        const float t1 = Cv * Dv;
        const float u  = (q & 1) ? (A * Bv) : ((q == 2) ? A : Bv);
        const float v  = (q == 1) ? 1.0f : t1;
        const float ez = NOISE * u * v;
        const float act = (g == 2) ? tanh_(ez) : sigmoid_(ez);  // valid at l<4

        // in-wave act broadcast (same bits round 11 moved through acts_lds)
        const float4 av = make_float4(rdlanef(act, 0), rdlanef(act, 1),
                                      rdlanef(act, 2), rdlanef(act, 3));

        // gate matvec for own gate g, h = 4l..4l+3 (round-11 dot4 chains)
        float4 gv4;
        gv4.x = bmg.x + dot4(wmg0, av);
        gv4.y = bmg.y + dot4(wmg1, av);
        gv4.z = bmg.z + dot4(wmg2, av);
        gv4.w = bmg.w + dot4(wmg3, av);
        *(float4*)&gates_lds[g][4 * l] = gv4;
        barrier_lds();                            // B1: gates visible

        // ---- phase B: cell update (reads own h's 4 gate values) -----------
        const float fv = gates_lds[0][t];
        const float iv = gates_lds[1][t];
        const float gvv = gates_lds[2][t];
        const float ov = gates_lds[3][t];

        cx = fmaf(fv, cx, iv * gvv);
        hx = ov * tanh_(cx);

        hx_lds[t] = hx;
        out_seq[((size_t)s * BATCH + b) * HID + t] = hx;
        barrier_lds();                            // B2: hx visible
    }

    out_hx[(size_t)b * HID + t] = hx;
    out_cx[(size_t)b * HID + t] = cx;
}

extern "C" void kernel_launch(void* const* d_in, const int* in_sizes, int n_in,
                              void* d_out, int out_size, void* d_ws, size_t ws_size,
                              hipStream_t stream) {
    const float* x     = (const float*)d_in[0];
    const float* w_lin = (const float*)d_in[1];
    const float* b_lin = (const float*)d_in[2];
    const float* w_map = (const float*)d_in[3];
    const float* b_map = (const float*)d_in[4];
    const float* theta = (const float*)d_in[5];
    float* out = (float*)d_out;

    const size_t pre_bytes = (size_t)SEQ * BATCH * 16 * sizeof(float);
    float* pre;
    int pstride;
    if (ws_size >= pre_bytes) {
        pre = (float*)d_ws;
        pstride = 16;
    } else {
        pre = out;                        // reads run >=2 rows ahead of writes
        pstride = HID;
    }

    pre_gemm<<<dim3(SEQ * 16), dim3(256), 0, stream>>>(x, w_lin, b_lin, theta, pre, pstride);
    qlstm_rec<<<dim3(BATCH), dim3(256), 0, stream>>>(w_lin, w_map, b_map, pre, pstride, out);
}

// Round 15
// 276.658 us; speedup vs baseline: 1.4899x; 1.0345x over previous
//
#include <hip/hip_runtime.h>

#define SEQ   512
#define BATCH 256
#define DIN   128
#define HID   256
#define NOISE 0.99f

__device__ __forceinline__ float dot4(float4 a, float4 b) {
    return fmaf(a.x, b.x, fmaf(a.y, b.y, fmaf(a.z, b.z, a.w * b.w)));
}
// round-11 validated activations (v_rcp; error bucket unchanged vs exact div)
__device__ __forceinline__ float sigmoid_(float x) {
    return __builtin_amdgcn_rcpf(1.0f + __expf(-x));
}
__device__ __forceinline__ float tanh_(float x) {
    float ax = fabsf(x);
    float e  = __expf(2.0f * ax);
    float t  = __builtin_amdgcn_rcpf(e + 1.0f);
    float r  = 1.0f - 2.0f * t;
    return copysignf(r, x);
}
template <int CTRL>
__device__ __forceinline__ float dppmov(float v) {
    return __int_as_float(__builtin_amdgcn_mov_dpp(__float_as_int(v), CTRL, 0xF, 0xF, false));
}
__device__ __forceinline__ float swap16_sum(float v) {
    float a = v, b;
    asm("v_mov_b32 %1, %0\n\tv_permlane16_swap_b32 %0, %1" : "+v"(a), "=&v"(b));
    return a + b;
}
__device__ __forceinline__ float swap32_sum(float v) {
    float a = v, b;
    asm("v_mov_b32 %1, %0\n\tv_permlane32_swap_b32 %0, %1" : "+v"(a), "=&v"(b));
    return a + b;
}
// LDS-only barrier (no vmcnt drain) — round-10 validated
__device__ __forceinline__ void barrier_lds() {
    asm volatile("s_waitcnt lgkmcnt(0)\n\ts_barrier" ::: "memory");
}
// loop-carried VGPR pin: forces the value to stay register-resident across
// iterations (empty asm, zero cost; "+v" = read-write ties it to a VGPR)
__device__ __forceinline__ void pin4(float4& v) {
    asm volatile("" : "+v"(v.x), "+v"(v.y), "+v"(v.z), "+v"(v.w));
}
__device__ __forceinline__ void pin1(float& v) {
    asm volatile("" : "+v"(v));
}

// ---------------------------------------------------------------------------
// Kernel 1: pre[s,b,p] (unchanged, validated rounds 2..14)
// ---------------------------------------------------------------------------
__global__ __launch_bounds__(256, 4) void pre_gemm(
    const float* __restrict__ x,
    const float* __restrict__ w_lin,
    const float* __restrict__ b_lin,
    const float* __restrict__ theta,
    float* pre, int pstride)
{
    __shared__ float wlds[16 * 132];
    const int t = threadIdx.x;
    for (int i = t; i < 16 * 128; i += 256) {
        int pp = i >> 7, dd = i & 127;
        wlds[pp * 132 + dd] = w_lin[pp * 384 + dd];
    }
    __syncthreads();
    const int s = blockIdx.x >> 4;
    const int b = ((blockIdx.x & 15) << 4) + (t >> 4);
    const int p = t & 15;
    const float* xr = x + ((size_t)s * BATCH + b) * DIN;
    const float* wr = &wlds[p * 132];
    float acc = b_lin[p] + theta[p];
    #pragma unroll 8
    for (int d = 0; d < 32; ++d)
        acc += dot4(*(const float4*)(xr + d * 4), *(const float4*)(wr + d * 4));
    pre[((size_t)s * BATCH + b) * pstride + p] = acc;
}

// ---------------------------------------------------------------------------
// Kernel 2: persistent recurrence — ROUND-11 KERNEL VERBATIM (bitwise) with
// ONE change: all 36 weight floats are pinned in VGPRs via in-loop empty-asm
// "+v" ties, eliminating the per-step weight reloads the VGPR=36 allocation
// implied (the ~430 cy/step unexplained stall).
// ---------------------------------------------------------------------------
__global__ __launch_bounds__(256, 1) void qlstm_rec(
    const float* __restrict__ w_lin,
    const float* __restrict__ w_map,
    const float* __restrict__ b_map,
    const float* pre, int pstride,    // may alias out (no restrict!)
    float* out)
{
    const int b = blockIdx.x;
    const int t = threadIdx.x;
    const int l = t & 63;
    const int g = t >> 6;        // wave index == gate
    const int q = l & 3;
    const int j = l >> 2;        // 0..15
    const int p = (g << 2) | q;

    __shared__ __align__(16) float hx_lds[HID];
    __shared__ __align__(16) float acts_lds[16];

    // hx-part weights; LDS-read slot k returns hx slot (k ^ sig), so load the
    // matching weight slot into register k (swizzle folded into init).
    const int sig = (j >> 1) & 3;
    const float* wp = w_lin + p * 384 + 128 + j * 16;
    float4 wh0 = *(const float4*)(wp + ((0 ^ sig) << 2));
    float4 wh1 = *(const float4*)(wp + ((1 ^ sig) << 2));
    float4 wh2 = *(const float4*)(wp + ((2 ^ sig) << 2));
    float4 wh3 = *(const float4*)(wp + ((3 ^ sig) << 2));

    // phase-2 weights: thread t owns h = t
    float4 wm0 = ((const float4*)w_map)[0 * 256 + t];
    float4 wm1 = ((const float4*)w_map)[1 * 256 + t];
    float4 wm2 = ((const float4*)w_map)[2 * 256 + t];
    float4 wm3 = ((const float4*)w_map)[3 * 256 + t];
    float bm0 = b_map[t];
    float bm1 = b_map[256 + t];
    float bm2 = b_map[512 + t];
    float bm3 = b_map[768 + t];

    // bank-conflict-free hx read addresses (XOR swizzle on the read side)
    const float* hr = &hx_lds[j * 16];
    const float* hr0 = hr + ((0 ^ sig) << 2);
    const float* hr1 = hr + ((1 ^ sig) << 2);
    const float* hr2 = hr + ((2 ^ sig) << 2);
    const float* hr3 = hr + ((3 ^ sig) << 2);

    // pre prefetch: 2 steps ahead (safe vs. the out-row overwrite when aliased)
    const float*  pb      = pre + (size_t)b * pstride + p;
    const size_t  sstride = (size_t)BATCH * pstride;
    float px0 = pb[0];
    float px1 = pb[sstride];

    hx_lds[t] = 0.0f;
    float hx = 0.0f, cx = 0.0f;
    float* out_seq = out;
    float* out_hx  = out + (size_t)SEQ * BATCH * HID;
    float* out_cx  = out_hx + BATCH * HID;
    barrier_lds();

    for (int s = 0; s < SEQ; ++s) {
        // ---- pin the weights: loop-carried VGPR residency (no reloads) ----
        pin4(wh0); pin4(wh1); pin4(wh2); pin4(wh3);
        pin4(wm0); pin4(wm1); pin4(wm2); pin4(wm3);
        pin1(bm0); pin1(bm1); pin1(bm2); pin1(bm3);

        const float pxu = px0;
        px0 = px1;
        const int s2 = (s + 2 < SEQ) ? s + 2 : SEQ - 1;
        px1 = pb[(size_t)s2 * sstride];

        // ---- phase 1: hx matvec + reduce (VALU comms) + quantum + act ------
        const float4 ha0 = *(const float4*)hr0;
        const float4 ha1 = *(const float4*)hr1;
        const float4 ha2 = *(const float4*)hr2;
        const float4 ha3 = *(const float4*)hr3;
        float acc = dot4(wh0, ha0) + dot4(wh1, ha1)
                  + dot4(wh2, ha2) + dot4(wh3, ha3);
        acc += dppmov<0x124>(acc);   // += lane+4  (row_ror:4)
        acc += dppmov<0x128>(acc);   // += lane+8  (row_ror:8)
        acc  = swap16_sum(acc);      // += lane^16
        acc  = swap32_sum(acc);      // += lane^32

        const float A  = __cosf(acc + pxu);      // pre includes b_lin + theta
        const float Bv = dppmov<0xB1>(A);        // quad_perm xor1 -> C_{q^1}
        const float Cv = dppmov<0x4E>(A);        // quad_perm xor2 -> C_{q^2}
        const float Dv = dppmov<0x4E>(Bv);       //                -> C_{q^3}

        const float t1 = Cv * Dv;
        const float u  = (q & 1) ? (A * Bv) : ((q == 2) ? A : Bv);
        const float v  = (q == 1) ? 1.0f : t1;
        const float ez = NOISE * u * v;
        const float act = (g == 2) ? tanh_(ez) : sigmoid_(ez);
        if (l < 4) acts_lds[(g << 2) | l] = act;
        barrier_lds();                            // B1: acts visible (LDS only)

        // ---- phase 2: gate matvec + cell update ---------------------------
        const float4 a0 = *(const float4*)&acts_lds[0];
        const float4 a1 = *(const float4*)&acts_lds[4];
        const float4 a2 = *(const float4*)&acts_lds[8];
        const float4 a3 = *(const float4*)&acts_lds[12];

        const float fv = bm0 + dot4(wm0, a0);
        const float iv = bm1 + dot4(wm1, a1);
        const float gv = bm2 + dot4(wm2, a2);
        const float ov = bm3 + dot4(wm3, a3);

        cx = fmaf(fv, cx, iv * gv);
        hx = ov * tanh_(cx);

        hx_lds[t] = hx;
        out_seq[((size_t)s * BATCH + b) * HID + t] = hx;
        barrier_lds();                            // B2: hx visible (LDS only)
    }

    out_hx[(size_t)b * HID + t] = hx;
    out_cx[(size_t)b * HID + t] = cx;
}

extern "C" void kernel_launch(void* const* d_in, const int* in_sizes, int n_in,
                              void* d_out, int out_size, void* d_ws, size_t ws_size,
                              hipStream_t stream) {
    const float* x     = (const float*)d_in[0];
    const float* w_lin = (const float*)d_in[1];
    const float* b_lin = (const float*)d_in[2];
    const float* w_map = (const float*)d_in[3];
    const float* b_map = (const float*)d_in[4];
    const float* theta = (const float*)d_in[5];
    float* out = (float*)d_out;

    const size_t pre_bytes = (size_t)SEQ * BATCH * 16 * sizeof(float);
    float* pre;
    int pstride;
    if (ws_size >= pre_bytes) {
        pre = (float*)d_ws;
        pstride = 16;
    } else {
        pre = out;                        // reads run >=2 rows ahead of writes
        pstride = HID;
    }

    pre_gemm<<<dim3(SEQ * 16), dim3(256), 0, stream>>>(x, w_lin, b_lin, theta, pre, pstride);
    qlstm_rec<<<dim3(BATCH), dim3(256), 0, stream>>>(w_lin, w_map, b_map, pre, pstride, out);
}

// Round 16
// 268.787 us; speedup vs baseline: 1.5335x; 1.0293x over previous
//
#include <hip/hip_runtime.h>

#define SEQ   512
#define BATCH 256
#define DIN   128
#define HID   256
#define NOISE 0.99f

__device__ __forceinline__ float dot4(float4 a, float4 b) {
    return fmaf(a.x, b.x, fmaf(a.y, b.y, fmaf(a.z, b.z, a.w * b.w)));
}
// round-11 validated activations (v_rcp; error bucket unchanged vs exact div)
__device__ __forceinline__ float sigmoid_(float x) {
    return __builtin_amdgcn_rcpf(1.0f + __expf(-x));
}
__device__ __forceinline__ float tanh_(float x) {
    float ax = fabsf(x);
    float e  = __expf(2.0f * ax);
    float t  = __builtin_amdgcn_rcpf(e + 1.0f);
    float r  = 1.0f - 2.0f * t;
    return copysignf(r, x);
}
template <int CTRL>
__device__ __forceinline__ float dppmov(float v) {
    return __int_as_float(__builtin_amdgcn_mov_dpp(__float_as_int(v), CTRL, 0xF, 0xF, false));
}
__device__ __forceinline__ float swap16_sum(float v) {
    float a = v, b;
    asm("v_mov_b32 %1, %0\n\tv_permlane16_swap_b32 %0, %1" : "+v"(a), "=&v"(b));
    return a + b;
}
__device__ __forceinline__ float swap32_sum(float v) {
    float a = v, b;
    asm("v_mov_b32 %1, %0\n\tv_permlane32_swap_b32 %0, %1" : "+v"(a), "=&v"(b));
    return a + b;
}
// LDS-only barrier (no vmcnt drain) — round-10 validated
__device__ __forceinline__ void barrier_lds() {
    asm volatile("s_waitcnt lgkmcnt(0)\n\ts_barrier" ::: "memory");
}

// ---------------------------------------------------------------------------
// Fused kernel: per-block prologue computes pre[s][p] for this block's batch
// element (bitwise pre_gemm arithmetic) into LDS; then the round-11 recurrence
// runs reading pre from LDS. One kernel, one launch, no global pre buffer.
// ---------------------------------------------------------------------------
__global__ __launch_bounds__(256, 1) void qlstm_fused(
    const float* __restrict__ x,      // (S,B,D)
    const float* __restrict__ w_lin,  // (16,384): x-part [0:128), hx-part [128:384)
    const float* __restrict__ b_lin,  // (16,)
    const float* __restrict__ w_map,  // (4,256,4)
    const float* __restrict__ b_map,  // (4,256)
    const float* __restrict__ theta,  // (16,)
    float* __restrict__ out)
{
    const int b = blockIdx.x;
    const int t = threadIdx.x;

    __shared__ __align__(16) float pre_lds[SEQ * 16];   // 32 KB
    __shared__ __align__(16) float wlds[16 * 132];      // 8.4 KB (prologue only)
    __shared__ __align__(16) float hx_lds[HID];
    __shared__ __align__(16) float acts_lds[16];

    // ================= prologue: pre[s][p], bitwise pre_gemm ===============
    for (int i = t; i < 16 * 128; i += 256) {
        int pp = i >> 7, dd = i & 127;
        wlds[pp * 132 + dd] = w_lin[pp * 384 + dd];
    }
    barrier_lds();
    {
        const int sp = t >> 4;            // s sub-row 0..15
        const int pp = t & 15;
        const float* wr = &wlds[pp * 132];
        const float bt = b_lin[pp] + theta[pp];
        for (int i = 0; i < 32; ++i) {
            const int s = i * 16 + sp;
            const float* xr = x + ((size_t)s * BATCH + b) * DIN;
            float acc = bt;
            #pragma unroll 8
            for (int d = 0; d < 32; ++d)
                acc += dot4(*(const float4*)(xr + d * 4), *(const float4*)(wr + d * 4));
            pre_lds[s * 16 + pp] = acc;   // addr linear in lane: conflict-free
        }
    }

    // ================= recurrence: round-11 verbatim, pre from LDS =========
    const int l = t & 63;
    const int g = t >> 6;        // wave index == gate
    const int q = l & 3;
    const int j = l >> 2;        // 0..15
    const int p = (g << 2) | q;

    // hx-part weights; LDS-read slot k returns hx slot (k ^ sig), so load the
    // matching weight slot into register k (swizzle folded into init).
    const int sig = (j >> 1) & 3;
    const float* wp = w_lin + p * 384 + 128 + j * 16;
    const float4 wh0 = *(const float4*)(wp + ((0 ^ sig) << 2));
    const float4 wh1 = *(const float4*)(wp + ((1 ^ sig) << 2));
    const float4 wh2 = *(const float4*)(wp + ((2 ^ sig) << 2));
    const float4 wh3 = *(const float4*)(wp + ((3 ^ sig) << 2));

    // phase-2 weights: thread t owns h = t
    const float4 wm0 = ((const float4*)w_map)[0 * 256 + t];
    const float4 wm1 = ((const float4*)w_map)[1 * 256 + t];
    const float4 wm2 = ((const float4*)w_map)[2 * 256 + t];
    const float4 wm3 = ((const float4*)w_map)[3 * 256 + t];
    const float bm0 = b_map[t];
    const float bm1 = b_map[256 + t];
    const float bm2 = b_map[512 + t];
    const float bm3 = b_map[768 + t];

    // bank-conflict-free hx read addresses (XOR swizzle on the read side)
    const float* hr = &hx_lds[j * 16];
    const float* hr0 = hr + ((0 ^ sig) << 2);
    const float* hr1 = hr + ((1 ^ sig) << 2);
    const float* hr2 = hr + ((2 ^ sig) << 2);
    const float* hr3 = hr + ((3 ^ sig) << 2);

    hx_lds[t] = 0.0f;
    float hx = 0.0f, cx = 0.0f;
    float* out_seq = out;
    float* out_hx  = out + (size_t)SEQ * BATCH * HID;
    float* out_cx  = out_hx + BATCH * HID;
    barrier_lds();               // pre_lds + hx_lds visible

    float px0 = pre_lds[p];      // 1-step-ahead prefetch from LDS

    for (int s = 0; s < SEQ; ++s) {
        const float pxu = px0;
        const int s1 = (s + 1 < SEQ) ? s + 1 : SEQ - 1;
        px0 = pre_lds[s1 * 16 + p];

        // ---- phase 1: hx matvec + reduce (VALU comms) + quantum + act ------
        const float4 ha0 = *(const float4*)hr0;
        const float4 ha1 = *(const float4*)hr1;
        const float4 ha2 = *(const float4*)hr2;
        const float4 ha3 = *(const float4*)hr3;
        float acc = dot4(wh0, ha0) + dot4(wh1, ha1)
                  + dot4(wh2, ha2) + dot4(wh3, ha3);
        acc += dppmov<0x124>(acc);   // += lane+4  (row_ror:4)
        acc += dppmov<0x128>(acc);   // += lane+8  (row_ror:8)
        acc  = swap16_sum(acc);      // += lane^16
        acc  = swap32_sum(acc);      // += lane^32

        const float A  = __cosf(acc + pxu);      // pre includes b_lin + theta
        const float Bv = dppmov<0xB1>(A);        // quad_perm xor1 -> C_{q^1}
        const float Cv = dppmov<0x4E>(A);        // quad_perm xor2 -> C_{q^2}
        const float Dv = dppmov<0x4E>(Bv);       //                -> C_{q^3}

        const float t1 = Cv * Dv;
        const float u  = (q & 1) ? (A * Bv) : ((q == 2) ? A : Bv);
        const float v  = (q == 1) ? 1.0f : t1;
        const float ez = NOISE * u * v;
        const float act = (g == 2) ? tanh_(ez) : sigmoid_(ez);
        if (l < 4) acts_lds[(g << 2) | l] = act;
        barrier_lds();                            // B1: acts visible (LDS only)

        // ---- phase 2: gate matvec + cell update ---------------------------
        const float4 a0 = *(const float4*)&acts_lds[0];
        const float4 a1 = *(const float4*)&acts_lds[4];
        const float4 a2 = *(const float4*)&acts_lds[8];
        const float4 a3 = *(const float4*)&acts_lds[12];

        const float fv = bm0 + dot4(wm0, a0);
        const float iv = bm1 + dot4(wm1, a1);
        const float gv = bm2 + dot4(wm2, a2);
        const float ov = bm3 + dot4(wm3, a3);

        cx = fmaf(fv, cx, iv * gv);
        hx = ov * tanh_(cx);

        hx_lds[t] = hx;
        out_seq[((size_t)s * BATCH + b) * HID + t] = hx;
        barrier_lds();                            // B2: hx visible (LDS only)
    }

    out_hx[(size_t)b * HID + t] = hx;
    out_cx[(size_t)b * HID + t] = cx;
}

extern "C" void kernel_launch(void* const* d_in, const int* in_sizes, int n_in,
                              void* d_out, int out_size, void* d_ws, size_t ws_size,
                              hipStream_t stream) {
    const float* x     = (const float*)d_in[0];
    const float* w_lin = (const float*)d_in[1];
    const float* b_lin = (const float*)d_in[2];
    const float* w_map = (const float*)d_in[3];
    const float* b_map = (const float*)d_in[4];
    const float* theta = (const float*)d_in[5];
    float* out = (float*)d_out;

    qlstm_fused<<<dim3(BATCH), dim3(256), 0, stream>>>(
        x, w_lin, b_lin, w_map, b_map, theta, out);
}

// Round 17
// 257.791 us; speedup vs baseline: 1.5989x; 1.0427x over previous
//
#include <hip/hip_runtime.h>

#define SEQ   512
#define BATCH 256
#define DIN   128
#define HID   256
#define NOISE 0.99f

__device__ __forceinline__ float dot4(float4 a, float4 b) {
    return fmaf(a.x, b.x, fmaf(a.y, b.y, fmaf(a.z, b.z, a.w * b.w)));
}
// round-11 validated activations (v_rcp; error bucket unchanged vs exact div)
__device__ __forceinline__ float sigmoid_(float x) {
    return __builtin_amdgcn_rcpf(1.0f + __expf(-x));
}
__device__ __forceinline__ float tanh_(float x) {
    float ax = fabsf(x);
    float e  = __expf(2.0f * ax);
    float t  = __builtin_amdgcn_rcpf(e + 1.0f);
    float r  = 1.0f - 2.0f * t;
    return copysignf(r, x);
}
template <int CTRL>
__device__ __forceinline__ float dppmov(float v) {
    return __int_as_float(__builtin_amdgcn_mov_dpp(__float_as_int(v), CTRL, 0xF, 0xF, false));
}
__device__ __forceinline__ float swap16_sum(float v) {
    float a = v, b;
    asm("v_mov_b32 %1, %0\n\tv_permlane16_swap_b32 %0, %1" : "+v"(a), "=&v"(b));
    return a + b;
}
__device__ __forceinline__ float swap32_sum(float v) {
    float a = v, b;
    asm("v_mov_b32 %1, %0\n\tv_permlane32_swap_b32 %0, %1" : "+v"(a), "=&v"(b));
    return a + b;
}
// LDS-only barrier (no vmcnt drain) — round-10 validated
__device__ __forceinline__ void barrier_lds() {
    asm volatile("s_waitcnt lgkmcnt(0)\n\ts_barrier" ::: "memory");
}

// ---------------------------------------------------------------------------
// Fused kernel. Prologue: pre[s][p] into LDS with COALESCED x loads staged
// through a double-buffered LDS chunk (16 s-rows), bitwise pre_gemm math.
// Then the round-11 recurrence (bitwise) reading pre from LDS.
// ---------------------------------------------------------------------------
__global__ __launch_bounds__(256, 1) void qlstm_fused(
    const float* __restrict__ x,      // (S,B,D)
    const float* __restrict__ w_lin,  // (16,384): x-part [0:128), hx-part [128:384)
    const float* __restrict__ b_lin,  // (16,)
    const float* __restrict__ w_map,  // (4,256,4)
    const float* __restrict__ b_map,  // (4,256)
    const float* __restrict__ theta,  // (16,)
    float* __restrict__ out)
{
    const int b = blockIdx.x;
    const int t = threadIdx.x;

    __shared__ __align__(16) float pre_lds[SEQ * 16];     // 32 KB
    __shared__ __align__(16) float wlds[16 * 132];        // 8.25 KB
    __shared__ __align__(16) float x_chunk[2][16][DIN];   // 16 KB
    __shared__ __align__(16) float hx_lds[HID];
    __shared__ __align__(16) float acts_lds[16];

    // ================= prologue: pre[s][p], bitwise pre_gemm ===============
    for (int i = t; i < 16 * 128; i += 256) {
        int pp = i >> 7, dd = i & 127;
        wlds[pp * 132 + dd] = w_lin[pp * 384 + dd];
    }

    const int xr_ = t >> 5;              // row 0..7 (and +8)
    const int xc_ = (t & 31) << 2;       // float col of this lane's float4
    auto xld = [&](int c, int r) -> float4 {   // coalesced: lanes span a row
        return *(const float4*)(x + ((size_t)((c << 4) + r) * BATCH + b) * DIN + xc_);
    };

    // stage chunk 0, prefetch chunk 1
    float4 ra = xld(0, xr_), rb = xld(0, xr_ + 8);
    *(float4*)&x_chunk[0][xr_][xc_]     = ra;
    *(float4*)&x_chunk[0][xr_ + 8][xc_] = rb;
    ra = xld(1, xr_); rb = xld(1, xr_ + 8);
    barrier_lds();                        // wlds + chunk0 visible

    const int sp = t >> 4;                // s sub-row 0..15
    const int pp = t & 15;
    const float* wr = &wlds[pp * 132];
    const float bt = b_lin[pp] + theta[pp];

    for (int c = 0; c < 32; ++c) {
        // compute chunk c from LDS (16-way broadcast reads: conflict-free)
        const float* xrow = x_chunk[c & 1][sp];
        float acc = bt;
        #pragma unroll 8
        for (int d = 0; d < 32; ++d)
            acc += dot4(*(const float4*)(xrow + d * 4), *(const float4*)(wr + d * 4));
        pre_lds[((c << 4) + sp) * 16 + pp] = acc;

        // commit prefetched chunk c+1, issue loads for chunk c+2
        if (c + 1 < 32) {
            *(float4*)&x_chunk[(c + 1) & 1][xr_][xc_]     = ra;
            *(float4*)&x_chunk[(c + 1) & 1][xr_ + 8][xc_] = rb;
            if (c + 2 < 32) { ra = xld(c + 2, xr_); rb = xld(c + 2, xr_ + 8); }
        }
        barrier_lds();
    }

    // ================= recurrence: round-11 verbatim, pre from LDS =========
    const int l = t & 63;
    const int g = t >> 6;        // wave index == gate
    const int q = l & 3;
    const int j = l >> 2;        // 0..15
    const int p = (g << 2) | q;

    const int sig = (j >> 1) & 3;
    const float* wp = w_lin + p * 384 + 128 + j * 16;
    const float4 wh0 = *(const float4*)(wp + ((0 ^ sig) << 2));
    const float4 wh1 = *(const float4*)(wp + ((1 ^ sig) << 2));
    const float4 wh2 = *(const float4*)(wp + ((2 ^ sig) << 2));
    const float4 wh3 = *(const float4*)(wp + ((3 ^ sig) << 2));

    const float4 wm0 = ((const float4*)w_map)[0 * 256 + t];
    const float4 wm1 = ((const float4*)w_map)[1 * 256 + t];
    const float4 wm2 = ((const float4*)w_map)[2 * 256 + t];
    const float4 wm3 = ((const float4*)w_map)[3 * 256 + t];
    const float bm0 = b_map[t];
    const float bm1 = b_map[256 + t];
    const float bm2 = b_map[512 + t];
    const float bm3 = b_map[768 + t];

    const float* hr = &hx_lds[j * 16];
    const float* hr0 = hr + ((0 ^ sig) << 2);
    const float* hr1 = hr + ((1 ^ sig) << 2);
    const float* hr2 = hr + ((2 ^ sig) << 2);
    const float* hr3 = hr + ((3 ^ sig) << 2);

    hx_lds[t] = 0.0f;
    float hx = 0.0f, cx = 0.0f;
    float* out_seq = out;
    float* out_hx  = out + (size_t)SEQ * BATCH * HID;
    float* out_cx  = out_hx + BATCH * HID;
    barrier_lds();               // pre_lds + hx_lds visible

    float px0 = pre_lds[p];      // 1-step-ahead prefetch from LDS

    for (int s = 0; s < SEQ; ++s) {
        const float pxu = px0;
        const int s1 = (s + 1 < SEQ) ? s + 1 : SEQ - 1;
        px0 = pre_lds[s1 * 16 + p];

        // ---- phase 1: hx matvec + reduce (VALU comms) + quantum + act ------
        const float4 ha0 = *(const float4*)hr0;
        const float4 ha1 = *(const float4*)hr1;
        const float4 ha2 = *(const float4*)hr2;
        const float4 ha3 = *(const float4*)hr3;
        float acc = dot4(wh0, ha0) + dot4(wh1, ha1)
                  + dot4(wh2, ha2) + dot4(wh3, ha3);
        acc += dppmov<0x124>(acc);   // += lane+4  (row_ror:4)
        acc += dppmov<0x128>(acc);   // += lane+8  (row_ror:8)
        acc  = swap16_sum(acc);      // += lane^16
        acc  = swap32_sum(acc);      // += lane^32

        const float A  = __cosf(acc + pxu);      // pre includes b_lin + theta
        const float Bv = dppmov<0xB1>(A);        // quad_perm xor1 -> C_{q^1}
        const float Cv = dppmov<0x4E>(A);        // quad_perm xor2 -> C_{q^2}
        const float Dv = dppmov<0x4E>(Bv);       //                -> C_{q^3}

        const float t1 = Cv * Dv;
        const float u  = (q & 1) ? (A * Bv) : ((q == 2) ? A : Bv);
        const float v  = (q == 1) ? 1.0f : t1;
        const float ez = NOISE * u * v;
        const float act = (g == 2) ? tanh_(ez) : sigmoid_(ez);
        if (l < 4) acts_lds[(g << 2) | l] = act;
        barrier_lds();                            // B1: acts visible (LDS only)

        // ---- phase 2: gate matvec + cell update ---------------------------
        const float4 a0 = *(const float4*)&acts_lds[0];
        const float4 a1 = *(const float4*)&acts_lds[4];
        const float4 a2 = *(const float4*)&acts_lds[8];
        const float4 a3 = *(const float4*)&acts_lds[12];

        const float fv = bm0 + dot4(wm0, a0);
        const float iv = bm1 + dot4(wm1, a1);
        const float gv = bm2 + dot4(wm2, a2);
        const float ov = bm3 + dot4(wm3, a3);

        cx = fmaf(fv, cx, iv * gv);
        hx = ov * tanh_(cx);

        hx_lds[t] = hx;
        out_seq[((size_t)s * BATCH + b) * HID + t] = hx;
        barrier_lds();                            // B2: hx visible (LDS only)
    }

    out_hx[(size_t)b * HID + t] = hx;
    out_cx[(size_t)b * HID + t] = cx;
}

extern "C" void kernel_launch(void* const* d_in, const int* in_sizes, int n_in,
                              void* d_out, int out_size, void* d_ws, size_t ws_size,
                              hipStream_t stream) {
    const float* x     = (const float*)d_in[0];
    const float* w_lin = (const float*)d_in[1];
    const float* b_lin = (const float*)d_in[2];
    const float* w_map = (const float*)d_in[3];
    const float* b_map = (const float*)d_in[4];
    const float* theta = (const float*)d_in[5];
    float* out = (float*)d_out;

    qlstm_fused<<<dim3(BATCH), dim3(256), 0, stream>>>(
        x, w_lin, b_lin, w_map, b_map, theta, out);
}